// Round 1
// baseline (2823.809 us; speedup 1.0000x reference)
//
#include <hip/hip_runtime.h>
#include <math.h>

namespace {

constexpr int B = 16, V = 325, T = 12, F = 64, K = 4, G = 3;
constexpr int D = T * F;                   // 768
constexpr int ATT_S = 168;                 // padded att row stride (163 -> 168, /4 and 16B aligned)
constexpr int OUT0 = B * V * T * F;        // 3,993,600 floats (gc_act)
constexpr int HT_SZ = G * K * 2 * V * F;   // 499,200 floats
constexpr float SLOPE_ = 325.0f;
constexpr float NEGINF = -9.0e15f;

__device__ __forceinline__ float leaky(float x) { return x >= 0.0f ? x : SLOPE_ * x; }

__device__ __forceinline__ float wsum(float v) {
#pragma unroll
  for (int m = 32; m >= 1; m >>= 1) v += __shfl_xor(v, m);
  return v;
}
__device__ __forceinline__ float wmax(float v) {
#pragma unroll
  for (int m = 32; m >= 1; m >>= 1) v = fmaxf(v, __shfl_xor(v, m));
  return v;
}

// ---------------------------------------------------------------------------
// K1: cluster[g,b,v,k] = softmax_k( dot(xv[b,v,:768], cw[g,k,:768]) )
// grid = B*V blocks, 256 threads (4 waves; wave w does (g,k) pairs w, w+4, w+8)
// ---------------------------------------------------------------------------
__global__ __launch_bounds__(256) void k_cluster(const float* __restrict__ x,
                                                 const float* __restrict__ cw,
                                                 float* __restrict__ out) {
  const int bv = blockIdx.x;
  const int lane = threadIdx.x & 63, wave = threadIdx.x >> 6;
  __shared__ float lg[12];
  const float* xr = x + bv * D;
  for (int p = wave; p < 12; p += 4) {
    const float* wr = cw + p * D;
    float s = 0.f;
#pragma unroll
    for (int m = 0; m < 12; ++m) {
      const int d = lane + 64 * m;
      s = fmaf(xr[d], wr[d], s);
    }
    s = wsum(s);
    if (lane == 0) lg[p] = s;
  }
  __syncthreads();
  if (threadIdx.x < 3) {
    const int g = threadIdx.x;
    float m = lg[g * 4];
    for (int k = 1; k < 4; ++k) m = fmaxf(m, lg[g * 4 + k]);
    float e[4], s = 0.f;
    for (int k = 0; k < 4; ++k) { e[k] = expf(lg[g * 4 + k] - m); s += e[k]; }
    const float inv = 1.f / s;
    const int b = bv / V, v = bv % V;
    float* o = out + OUT0 + ((g * B + b) * V + v) * K;
    for (int k = 0; k < 4; ++k) o[k] = e[k] * inv;
  }
}

// ---------------------------------------------------------------------------
// K2: ht[gko, v, f] = (1/B) sum_{b,t} leaky( x[b,v,t,:] . W[gko,f,:] + Wb[gko,f] ) * Wt[gko,t]
// grid = 24*V blocks (one per (gko, v)), 256 threads.
// ---------------------------------------------------------------------------
__global__ __launch_bounds__(256) void k_ht(const float* __restrict__ x,
                                            const float* __restrict__ W,
                                            const float* __restrict__ Wbias,
                                            const float* __restrict__ Wt,
                                            float* __restrict__ ht) {
  const int bid = blockIdx.x;
  const int v = bid % V;
  const int gko = bid / V;  // ((g*K+k)*2+o)
  const int tid = threadIdx.x;
  const int lane = tid & 63, grp = tid >> 6;

  __shared__ float xb[192][64];   // all (b,t) rows for this v
  __shared__ float Wl[64][68];    // W[f][c], padded to kill b128 bank conflicts
  __shared__ float Wbl[64];
  __shared__ float Wtl[12];
  __shared__ float red[4][64];

  for (int idx = tid; idx < 192 * 16; idx += 256) {
    const int row = idx >> 4, c4 = idx & 15;
    const int bb = row / 12, tt = row % 12;
    *(float4*)(&xb[row][c4 * 4]) =
        *(const float4*)(x + ((bb * V + v) * T + tt) * F + c4 * 4);
  }
  {
    const float* Wg = W + gko * (F * F);
    for (int idx = tid; idx < 64 * 16; idx += 256) {
      const int f = idx >> 4, c4 = idx & 15;
      *(float4*)(&Wl[f][c4 * 4]) = *(const float4*)(Wg + f * 64 + c4 * 4);
    }
    if (tid < 64) Wbl[tid] = Wbias[gko * 64 + tid];
    if (tid < 12) Wtl[tid] = Wt[gko * 12 + tid];
  }
  __syncthreads();

  float acc = 0.f;
  for (int ch = 0; ch < 12; ++ch) {
    const int bt0 = grp * 48 + ch * 4;
    float p0 = Wbl[lane], p1 = p0, p2 = p0, p3 = p0;
#pragma unroll
    for (int c4 = 0; c4 < 16; ++c4) {
      const float4 w4 = *(const float4*)(&Wl[lane][c4 * 4]);
      const float4 x0 = *(const float4*)(&xb[bt0 + 0][c4 * 4]);
      const float4 x1 = *(const float4*)(&xb[bt0 + 1][c4 * 4]);
      const float4 x2 = *(const float4*)(&xb[bt0 + 2][c4 * 4]);
      const float4 x3 = *(const float4*)(&xb[bt0 + 3][c4 * 4]);
      p0 = fmaf(x0.x, w4.x, p0); p0 = fmaf(x0.y, w4.y, p0); p0 = fmaf(x0.z, w4.z, p0); p0 = fmaf(x0.w, w4.w, p0);
      p1 = fmaf(x1.x, w4.x, p1); p1 = fmaf(x1.y, w4.y, p1); p1 = fmaf(x1.z, w4.z, p1); p1 = fmaf(x1.w, w4.w, p1);
      p2 = fmaf(x2.x, w4.x, p2); p2 = fmaf(x2.y, w4.y, p2); p2 = fmaf(x2.z, w4.z, p2); p2 = fmaf(x2.w, w4.w, p2);
      p3 = fmaf(x3.x, w4.x, p3); p3 = fmaf(x3.y, w4.y, p3); p3 = fmaf(x3.z, w4.z, p3); p3 = fmaf(x3.w, w4.w, p3);
    }
    acc = fmaf(leaky(p0), Wtl[(bt0 + 0) % 12], acc);
    acc = fmaf(leaky(p1), Wtl[(bt0 + 1) % 12], acc);
    acc = fmaf(leaky(p2), Wtl[(bt0 + 2) % 12], acc);
    acc = fmaf(leaky(p3), Wtl[(bt0 + 3) % 12], acc);
  }
  red[grp][lane] = acc;
  __syncthreads();
  if (grp == 0) {
    const float s = (red[0][lane] + red[1][lane] + red[2][lane] + red[3][lane]) * (1.0f / 16.0f);
    ht[bid * 64 + lane] = s;
  }
}

// ---------------------------------------------------------------------------
// K3: att[gko, i, j] = softmax_j over masked leaky(s1[j]+s2[i]),
//     s1[j] = ht[gko, o+2j, :].a1 , s2[i] = ht[gko, i, :].a2
// grid = 24 blocks, 256 threads. Rows padded to ATT_S with zeros.
// ---------------------------------------------------------------------------
__global__ __launch_bounds__(256) void k_att(const float* __restrict__ ht,
                                             const float* __restrict__ a,
                                             const int* __restrict__ adj,
                                             float* __restrict__ att) {
  const int gko = blockIdx.x;
  const int o = gko & 1;
  const int g = (gko >> 1) >> 2;
  const int Vs = o ? 162 : 163;
  const int tid = threadIdx.x, lane = tid & 63, wave = tid >> 6;
  __shared__ float s1[163], s2[325];
  const float* htg = ht + gko * (V * F);
  const float* a1 = a + gko * 128;
  const float* a2 = a1 + 64;

  for (int d = wave; d < 325 + Vs; d += 4) {
    int row; const float* av;
    if (d < 325) { row = d;              av = a2; }
    else         { row = o + 2 * (d - 325); av = a1; }
    float s = htg[row * 64 + lane] * av[lane];
    s = wsum(s);
    if (lane == 0) { if (d < 325) s2[d] = s; else s1[d - 325] = s; }
  }
  __syncthreads();

  const int* adjg = adj + g * (V * V);
  for (int i = wave; i < V; i += 4) {
    const float e0 = s2[i];
    float vj[3];
    float mx = NEGINF;
#pragma unroll
    for (int r = 0; r < 3; ++r) {
      const int j = lane + 64 * r;
      float val = NEGINF;
      if (j < Vs) {
        const float e = leaky(s1[j] + e0);
        const int ad = adjg[i * V + (o + 2 * j)];
        val = (ad > 0) ? e : NEGINF;
      }
      vj[r] = val;
      mx = fmaxf(mx, val);
    }
    mx = wmax(mx);
    float sum = 0.f, ex[3];
#pragma unroll
    for (int r = 0; r < 3; ++r) {
      const int j = lane + 64 * r;
      const float tt = (j < Vs) ? expf(vj[r] - mx) : 0.f;
      ex[r] = tt; sum += tt;
    }
    sum = wsum(sum);
    const float inv = 1.f / sum;
    float* ar = att + (gko * V + i) * ATT_S;
#pragma unroll
    for (int r = 0; r < 3; ++r) {
      const int j = lane + 64 * r;
      if (j < ATT_S) ar[j] = (j < Vs) ? ex[r] * inv : 0.f;
    }
  }
}

// ---------------------------------------------------------------------------
// K4: per (b,t,g,o): loop k: build h_sub[j,f]=leaky(x[b,node_j,t,:].W+Wb) in LDS,
//     hp[i,f] = sum_j att[i,j]*h_sub[j,f]; oacc[i,f] += leaky(hp)*cluster[g,b,i,k].
//     atomicAdd(out, oacc/G) across the 6 (g,o) blocks per (b,t).
// grid = B*T*G*2 = 1152 blocks, 1024 threads (16 waves; wave owns i = wave+16*q).
// ---------------------------------------------------------------------------
__global__ __launch_bounds__(1024) void k_hp(const float* __restrict__ x,
                                             const float* __restrict__ W,
                                             const float* __restrict__ Wbias,
                                             const float* __restrict__ att,
                                             const float* __restrict__ cluster,
                                             float* __restrict__ out) {
  const int bid = blockIdx.x;
  const int o = bid & 1;
  const int g = (bid >> 1) % 3;
  const int bt = bid / 6;
  const int t = bt % 12;
  const int b = bt / 12;
  const int Vs = o ? 162 : 163;
  const int tid = threadIdx.x;
  const int lane = tid & 63;
  const int wave = tid >> 6;

  __shared__ float xs[163][64];
  __shared__ float Wl[64][68];
  __shared__ float hs[ATT_S][64];
  __shared__ float Wbl[64];
  __shared__ float cl[325];

  for (int idx = tid; idx < 163 * 16; idx += 1024) {
    const int j = idx >> 4, c4 = idx & 15;
    float4 v4 = make_float4(0.f, 0.f, 0.f, 0.f);
    if (j < Vs) {
      const int node = o + 2 * j;
      v4 = *(const float4*)(x + ((b * V + node) * T + t) * F + c4 * 4);
    }
    *(float4*)(&xs[j][c4 * 4]) = v4;
  }

  float oacc[24];
#pragma unroll
  for (int q = 0; q < 24; ++q) oacc[q] = 0.f;

  for (int k = 0; k < K; ++k) {
    const int gko = (g * K + k) * 2 + o;
    __syncthreads();  // previous-iteration consumers done before restage
    {
      const float* Wg = W + gko * (F * F);
      const int f = tid >> 4, c4 = tid & 15;
      *(float4*)(&Wl[f][c4 * 4]) = *(const float4*)(Wg + f * 64 + c4 * 4);
      if (tid < 64) Wbl[tid] = Wbias[gko * 64 + tid];
      for (int i = tid; i < V; i += 1024)
        cl[i] = cluster[((g * B + b) * V + i) * K + k];
    }
    __syncthreads();

    // h_sub build: wave = j-group, 64 lanes = f
    for (int j = wave; j < ATT_S; j += 16) {
      float p = 0.f;
      if (j < Vs) {
        p = Wbl[lane];
#pragma unroll
        for (int c4 = 0; c4 < 16; ++c4) {
          const float4 w4 = *(const float4*)(&Wl[lane][c4 * 4]);
          const float4 x4 = *(const float4*)(&xs[j][c4 * 4]);
          p = fmaf(x4.x, w4.x, p);
          p = fmaf(x4.y, w4.y, p);
          p = fmaf(x4.z, w4.z, p);
          p = fmaf(x4.w, w4.w, p);
        }
        p = leaky(p);
      }
      hs[j][lane] = p;  // zero pad rows: keeps att-pad products finite
    }
    __syncthreads();

    const float* attg = att + gko * (V * ATT_S);
    for (int cc = 0; cc < 6; ++cc) {
      const int ii0 = cc * 4;
      const int i0 = wave + 16 * (ii0 + 0);
      if (i0 >= V) break;
      const int i1 = wave + 16 * (ii0 + 1);
      const int i2 = wave + 16 * (ii0 + 2);
      const int i3 = wave + 16 * (ii0 + 3);
      const float* r0 = attg + min(i0, V - 1) * ATT_S;
      const float* r1 = attg + min(i1, V - 1) * ATT_S;
      const float* r2 = attg + min(i2, V - 1) * ATT_S;
      const float* r3 = attg + min(i3, V - 1) * ATT_S;
      float a0 = 0.f, a1 = 0.f, a2 = 0.f, a3 = 0.f;
#pragma unroll 2
      for (int j4 = 0; j4 < ATT_S / 4; ++j4) {
        const float4 t0 = *(const float4*)(r0 + j4 * 4);
        const float4 t1 = *(const float4*)(r1 + j4 * 4);
        const float4 t2 = *(const float4*)(r2 + j4 * 4);
        const float4 t3 = *(const float4*)(r3 + j4 * 4);
        const float h0 = hs[j4 * 4 + 0][lane];
        const float h1 = hs[j4 * 4 + 1][lane];
        const float h2 = hs[j4 * 4 + 2][lane];
        const float h3 = hs[j4 * 4 + 3][lane];
        a0 = fmaf(t0.x, h0, a0); a0 = fmaf(t0.y, h1, a0); a0 = fmaf(t0.z, h2, a0); a0 = fmaf(t0.w, h3, a0);
        a1 = fmaf(t1.x, h0, a1); a1 = fmaf(t1.y, h1, a1); a1 = fmaf(t1.z, h2, a1); a1 = fmaf(t1.w, h3, a1);
        a2 = fmaf(t2.x, h0, a2); a2 = fmaf(t2.y, h1, a2); a2 = fmaf(t2.z, h2, a2); a2 = fmaf(t2.w, h3, a2);
        a3 = fmaf(t3.x, h0, a3); a3 = fmaf(t3.y, h1, a3); a3 = fmaf(t3.z, h2, a3); a3 = fmaf(t3.w, h3, a3);
      }
      const float w0 = cl[i0];
      const float w1 = (i1 < V) ? cl[min(i1, V - 1)] : 0.f;
      const float w2 = (i2 < V) ? cl[min(i2, V - 1)] : 0.f;
      const float w3 = (i3 < V) ? cl[min(i3, V - 1)] : 0.f;
      oacc[ii0 + 0] += leaky(a0) * w0;
      oacc[ii0 + 1] += leaky(a1) * w1;
      oacc[ii0 + 2] += leaky(a2) * w2;
      oacc[ii0 + 3] += leaky(a3) * w3;
    }
  }

#pragma unroll
  for (int q = 0; q < 24; ++q) {
    const int i = wave + 16 * q;
    if (i < V)
      atomicAdd(out + ((b * V + i) * T + t) * F + lane, oacc[q] * (1.0f / 3.0f));
  }
}

}  // namespace

extern "C" void kernel_launch(void* const* d_in, const int* in_sizes, int n_in,
                              void* d_out, int out_size, void* d_ws, size_t ws_size,
                              hipStream_t stream) {
  const float* x   = (const float*)d_in[0];
  const int*   adj = (const int*)d_in[1];
  const float* W   = (const float*)d_in[2];
  const float* Wb  = (const float*)d_in[3];
  const float* Wt  = (const float*)d_in[4];
  const float* a   = (const float*)d_in[5];
  const float* cw  = (const float*)d_in[6];
  float* out = (float*)d_out;
  float* ws  = (float*)d_ws;

  float* ht  = ws;            // HT_SZ floats
  float* att = ws + HT_SZ;    // 24*V*ATT_S floats  (~7.2 MB total ws use)

  hipMemsetAsync(out, 0, (size_t)OUT0 * sizeof(float), stream);
  k_cluster<<<B * V, 256, 0, stream>>>(x, cw, out);
  k_ht<<<G * K * 2 * V, 256, 0, stream>>>(x, W, Wb, Wt, ht);
  k_att<<<G * K * 2, 256, 0, stream>>>(ht, a, adj, att);
  k_hp<<<B * T * G * 2, 1024, 0, stream>>>(x, W, Wb, att, out + OUT0, out);
}

// Round 2
// 847.425 us; speedup vs baseline: 3.3322x; 3.3322x over previous
//
#include <hip/hip_runtime.h>
#include <math.h>

namespace {

typedef __attribute__((ext_vector_type(8))) short bf16x8;
typedef __attribute__((ext_vector_type(4))) float f32x4;

constexpr int B = 16, V = 325, T = 12, F = 64, K = 4, G = 3;
constexpr int D = T * F;                   // 768
constexpr int ATT_R = 336;                 // padded rows (325 -> 336 = 21*16)
constexpr int ATT_S = 192;                 // padded K dim (163 -> 192 = 6*32), bf16
constexpr int OUT0 = B * V * T * F;        // 3,993,600 floats (gc_act)
constexpr int HT_SZ = G * K * 2 * V * F;   // 499,200 floats
constexpr float SLOPE_ = 325.0f;
constexpr float NEGINF = -9.0e15f;

__device__ __forceinline__ float leaky(float x) { return x >= 0.0f ? x : SLOPE_ * x; }

__device__ __forceinline__ unsigned short f2bf(float f) {
  unsigned int u = __float_as_uint(f);
  u = (u + 0x7fffu + ((u >> 16) & 1u)) >> 16;   // RNE
  return (unsigned short)u;
}

__device__ __forceinline__ float wsum(float v) {
#pragma unroll
  for (int m = 32; m >= 1; m >>= 1) v += __shfl_xor(v, m);
  return v;
}
__device__ __forceinline__ float wmax(float v) {
#pragma unroll
  for (int m = 32; m >= 1; m >>= 1) v = fmaxf(v, __shfl_xor(v, m));
  return v;
}

// ---------------------------------------------------------------------------
// K1: cluster[g,b,v,k] = softmax_k( dot(xv[b,v,:768], cw[g,k,:768]) )
// ---------------------------------------------------------------------------
__global__ __launch_bounds__(256) void k_cluster(const float* __restrict__ x,
                                                 const float* __restrict__ cw,
                                                 float* __restrict__ out) {
  const int bv = blockIdx.x;
  const int lane = threadIdx.x & 63, wave = threadIdx.x >> 6;
  __shared__ float lg[12];
  const float* xr = x + bv * D;
  for (int p = wave; p < 12; p += 4) {
    const float* wr = cw + p * D;
    float s = 0.f;
#pragma unroll
    for (int m = 0; m < 12; ++m) {
      const int d = lane + 64 * m;
      s = fmaf(xr[d], wr[d], s);
    }
    s = wsum(s);
    if (lane == 0) lg[p] = s;
  }
  __syncthreads();
  if (threadIdx.x < 3) {
    const int g = threadIdx.x;
    float m = lg[g * 4];
    for (int k = 1; k < 4; ++k) m = fmaxf(m, lg[g * 4 + k]);
    float e[4], s = 0.f;
    for (int k = 0; k < 4; ++k) { e[k] = expf(lg[g * 4 + k] - m); s += e[k]; }
    const float inv = 1.f / s;
    const int b = bv / V, v = bv % V;
    float* o = out + OUT0 + ((g * B + b) * V + v) * K;
    for (int k = 0; k < 4; ++k) o[k] = e[k] * inv;
  }
}

// ---------------------------------------------------------------------------
// K2: ht[gko, v, f] = (1/B) sum_{b,t} leaky( x[b,v,t,:].W[gko,f,:] + Wb ) * Wt[t]
// ---------------------------------------------------------------------------
__global__ __launch_bounds__(256) void k_ht(const float* __restrict__ x,
                                            const float* __restrict__ W,
                                            const float* __restrict__ Wbias,
                                            const float* __restrict__ Wt,
                                            float* __restrict__ ht) {
  const int bid = blockIdx.x;
  const int v = bid % V;
  const int gko = bid / V;
  const int tid = threadIdx.x;
  const int lane = tid & 63, grp = tid >> 6;

  __shared__ float xb[192][64];
  __shared__ float Wl[64][68];
  __shared__ float Wbl[64];
  __shared__ float Wtl[12];
  __shared__ float red[4][64];

  for (int idx = tid; idx < 192 * 16; idx += 256) {
    const int row = idx >> 4, c4 = idx & 15;
    const int bb = row / 12, tt = row % 12;
    *(float4*)(&xb[row][c4 * 4]) =
        *(const float4*)(x + ((bb * V + v) * T + tt) * F + c4 * 4);
  }
  {
    const float* Wg = W + gko * (F * F);
    for (int idx = tid; idx < 64 * 16; idx += 256) {
      const int f = idx >> 4, c4 = idx & 15;
      *(float4*)(&Wl[f][c4 * 4]) = *(const float4*)(Wg + f * 64 + c4 * 4);
    }
    if (tid < 64) Wbl[tid] = Wbias[gko * 64 + tid];
    if (tid < 12) Wtl[tid] = Wt[gko * 12 + tid];
  }
  __syncthreads();

  float acc = 0.f;
  for (int ch = 0; ch < 12; ++ch) {
    const int bt0 = grp * 48 + ch * 4;
    float p0 = Wbl[lane], p1 = p0, p2 = p0, p3 = p0;
#pragma unroll
    for (int c4 = 0; c4 < 16; ++c4) {
      const float4 w4 = *(const float4*)(&Wl[lane][c4 * 4]);
      const float4 x0 = *(const float4*)(&xb[bt0 + 0][c4 * 4]);
      const float4 x1 = *(const float4*)(&xb[bt0 + 1][c4 * 4]);
      const float4 x2 = *(const float4*)(&xb[bt0 + 2][c4 * 4]);
      const float4 x3 = *(const float4*)(&xb[bt0 + 3][c4 * 4]);
      p0 = fmaf(x0.x, w4.x, p0); p0 = fmaf(x0.y, w4.y, p0); p0 = fmaf(x0.z, w4.z, p0); p0 = fmaf(x0.w, w4.w, p0);
      p1 = fmaf(x1.x, w4.x, p1); p1 = fmaf(x1.y, w4.y, p1); p1 = fmaf(x1.z, w4.z, p1); p1 = fmaf(x1.w, w4.w, p1);
      p2 = fmaf(x2.x, w4.x, p2); p2 = fmaf(x2.y, w4.y, p2); p2 = fmaf(x2.z, w4.z, p2); p2 = fmaf(x2.w, w4.w, p2);
      p3 = fmaf(x3.x, w4.x, p3); p3 = fmaf(x3.y, w4.y, p3); p3 = fmaf(x3.z, w4.z, p3); p3 = fmaf(x3.w, w4.w, p3);
    }
    acc = fmaf(leaky(p0), Wtl[(bt0 + 0) % 12], acc);
    acc = fmaf(leaky(p1), Wtl[(bt0 + 1) % 12], acc);
    acc = fmaf(leaky(p2), Wtl[(bt0 + 2) % 12], acc);
    acc = fmaf(leaky(p3), Wtl[(bt0 + 3) % 12], acc);
  }
  red[grp][lane] = acc;
  __syncthreads();
  if (grp == 0) {
    const float s = (red[0][lane] + red[1][lane] + red[2][lane] + red[3][lane]) * (1.0f / 16.0f);
    ht[bid * 64 + lane] = s;
  }
}

// ---------------------------------------------------------------------------
// K3: att[gko, i, j] = softmax_j over masked leaky(s1[j]+s2[i]) -> bf16,
//     padded to [ATT_R=336][ATT_S=192] with zeros.
// ---------------------------------------------------------------------------
__global__ __launch_bounds__(256) void k_att(const float* __restrict__ ht,
                                             const float* __restrict__ a,
                                             const int* __restrict__ adj,
                                             unsigned short* __restrict__ att) {
  const int gko = blockIdx.x;
  const int o = gko & 1;
  const int g = gko >> 3;  // gko = ((g*4+k)*2+o)
  const int Vs = o ? 162 : 163;
  const int tid = threadIdx.x, lane = tid & 63, wave = tid >> 6;
  __shared__ float s1[163], s2[325];
  const float* htg = ht + gko * (V * F);
  const float* a1 = a + gko * 128;
  const float* a2 = a1 + 64;

  for (int d = wave; d < 325 + Vs; d += 4) {
    int row; const float* av;
    if (d < 325) { row = d;                 av = a2; }
    else         { row = o + 2 * (d - 325); av = a1; }
    float s = htg[row * 64 + lane] * av[lane];
    s = wsum(s);
    if (lane == 0) { if (d < 325) s2[d] = s; else s1[d - 325] = s; }
  }
  __syncthreads();

  const int* adjg = adj + g * (V * V);
  for (int i = wave; i < V; i += 4) {
    const float e0 = s2[i];
    float vj[3];
    float mx = NEGINF;
#pragma unroll
    for (int r = 0; r < 3; ++r) {
      const int j = lane + 64 * r;
      float val = NEGINF;
      if (j < Vs) {
        const float e = leaky(s1[j] + e0);
        const int ad = adjg[i * V + (o + 2 * j)];
        val = (ad > 0) ? e : NEGINF;
      }
      vj[r] = val;
      mx = fmaxf(mx, val);
    }
    mx = wmax(mx);
    float sum = 0.f, ex[3];
#pragma unroll
    for (int r = 0; r < 3; ++r) {
      const int j = lane + 64 * r;
      const float tt = (j < Vs) ? expf(vj[r] - mx) : 0.f;
      ex[r] = tt; sum += tt;
    }
    sum = wsum(sum);
    const float inv = 1.f / sum;
    unsigned short* ar = att + ((size_t)gko * ATT_R + i) * ATT_S;
#pragma unroll
    for (int r = 0; r < 3; ++r) {
      const int j = lane + 64 * r;  // covers 0..191 = ATT_S
      ar[j] = (j < Vs) ? f2bf(ex[r] * inv) : 0;
    }
  }
  // zero pad rows 325..335
  unsigned short* zb = att + ((size_t)gko * ATT_R + 325) * ATT_S;
  for (int idx = tid; idx < (ATT_R - V) * ATT_S; idx += 256) zb[idx] = 0;
}

// ---------------------------------------------------------------------------
// K4 (MFMA): per block (g,o,b,t), loop k:
//   H-build: H[j,f] = leaky(X[j,:].W[f,:] + b)  via mfma, bf16 -> LDS Ht[f][j]
//   C-GEMM : hp[i,f] = sum_j att_bf16[i,j] * H[j,f] via mfma
//   accO   += leaky(hp) * cluster[g,b,i,k]
// atomicAdd(out, accO/3).
// Fragment layouts (16x16x32 bf16): A: row=l&15, k=8*(l>>4)+e ; B: col=l&15,
// k=8*(l>>4)+e ; C/D: col=l&15, row=4*(l>>4)+r  [guide §3, m89-verified].
// LDS rows at 128B/384B stride -> XOR swizzle byte ^= (row&7)<<4 (G4).
// ---------------------------------------------------------------------------
__global__ __launch_bounds__(512, 2) void k_hp(const float* __restrict__ x,
                                               const float* __restrict__ W,
                                               const float* __restrict__ Wbias,
                                               const unsigned short* __restrict__ att,
                                               const float* __restrict__ cluster,
                                               float* __restrict__ out) {
  const int bid = blockIdx.x;
  const int o = bid & 1;
  const int g = (bid >> 1) % 3;
  const int bt = bid / 6;
  const int t = bt % 12;
  const int b = bt / 12;
  const int Vs = o ? 162 : 163;
  const int tid = threadIdx.x;
  const int lane = tid & 63;
  const int wv = tid >> 6;       // 8 waves
  const int lr = lane & 15;      // tile row/col
  const int lg = lane >> 4;      // k-group

  __shared__ unsigned short Xl[176 * 64];    // bf16, swizzled, 22.5 KB
  __shared__ unsigned short Wlb[64 * 64];    // bf16, swizzled, 8 KB
  __shared__ unsigned short Htl[64 * 192];   // bf16 H^T [f][j], swizzled, 24.6 KB
  __shared__ float biasl[64];
  __shared__ float cll[336 * 4];

  // ---- stage X as bf16 (rows >= Vs zero), swizzled ----
  for (int idx = tid; idx < 176 * 8; idx += 512) {
    const int j = idx >> 3, c0 = (idx & 7) * 8;
    union { unsigned short u[8]; uint4 q; } P;
    if (j < Vs) {
      const float* xp = x + ((b * V + (o + 2 * j)) * T + t) * F + c0;
      const float4 x0 = *(const float4*)xp;
      const float4 x1 = *(const float4*)(xp + 4);
      P.u[0] = f2bf(x0.x); P.u[1] = f2bf(x0.y); P.u[2] = f2bf(x0.z); P.u[3] = f2bf(x0.w);
      P.u[4] = f2bf(x1.x); P.u[5] = f2bf(x1.y); P.u[6] = f2bf(x1.z); P.u[7] = f2bf(x1.w);
    } else {
      P.q = make_uint4(0, 0, 0, 0);
    }
    *(uint4*)((char*)Xl + ((j * 128 + c0 * 2) ^ ((j & 7) << 4))) = P.q;
  }
  // ---- stage cluster weights (i >= 325 zero) ----
  for (int i = tid; i < 336; i += 512) {
    float4 c4 = make_float4(0.f, 0.f, 0.f, 0.f);
    if (i < V) c4 = *(const float4*)(cluster + ((g * B + b) * V + i) * K);
    *(float4*)&cll[i * 4] = c4;
  }
  // ---- zero Ht (covers K-pad cols 176..191 permanently) ----
  for (int idx = tid; idx < (64 * 192) / 8; idx += 512)
    ((uint4*)Htl)[idx] = make_uint4(0, 0, 0, 0);

  f32x4 accO[3][4];
#pragma unroll
  for (int s = 0; s < 3; ++s)
#pragma unroll
    for (int n = 0; n < 4; ++n) accO[s][n] = (f32x4){0.f, 0.f, 0.f, 0.f};

  for (int k = 0; k < K; ++k) {
    const int gko = (g * K + k) * 2 + o;
    __syncthreads();  // prev C-GEMM readers of Htl/Wlb done
    // ---- stage W (bf16, swizzled) + bias ----
    {
      const int f = tid >> 3, c0 = (tid & 7) * 8;
      const float* wp = W + gko * (F * F) + f * 64 + c0;
      const float4 w0 = *(const float4*)wp;
      const float4 w1 = *(const float4*)(wp + 4);
      union { unsigned short u[8]; uint4 q; } P;
      P.u[0] = f2bf(w0.x); P.u[1] = f2bf(w0.y); P.u[2] = f2bf(w0.z); P.u[3] = f2bf(w0.w);
      P.u[4] = f2bf(w1.x); P.u[5] = f2bf(w1.y); P.u[6] = f2bf(w1.z); P.u[7] = f2bf(w1.w);
      *(uint4*)((char*)Wlb + ((f * 128 + c0 * 2) ^ ((f & 7) << 4))) = P.q;
      if (tid < 64) biasl[tid] = Wbias[gko * 64 + tid];
    }
    __syncthreads();

    // ---- H-build: 11 Mtiles x 4 Ntiles, K=64 (2 steps) ----
    for (int s = 0; s < 6; ++s) {
      const int p = wv + 8 * s;
      if (p < 44) {
        const int mt = p >> 2, n = p & 3;
        f32x4 acc = (f32x4){0.f, 0.f, 0.f, 0.f};
#pragma unroll
        for (int kst = 0; kst < 2; ++kst) {
          const int j = mt * 16 + lr, k0 = kst * 32 + lg * 8;
          const bf16x8 af = *(const bf16x8*)((const char*)Xl + ((j * 128 + k0 * 2) ^ ((j & 7) << 4)));
          const int f = n * 16 + lr;
          const bf16x8 bf = *(const bf16x8*)((const char*)Wlb + ((f * 128 + k0 * 2) ^ ((f & 7) << 4)));
          acc = __builtin_amdgcn_mfma_f32_16x16x32_bf16(af, bf, acc, 0, 0, 0);
        }
        const int f = n * 16 + lr;
        const float bv = biasl[f];
        const int j0 = mt * 16 + lg * 4;
        union { unsigned short u[4]; uint2 q; } Pk;
#pragma unroll
        for (int r = 0; r < 4; ++r) {
          const float val = leaky(acc[r] + bv);
          Pk.u[r] = (j0 + r < Vs) ? f2bf(val) : 0;
        }
        *(uint2*)((char*)Htl + ((f * 384 + j0 * 2) ^ ((f & 7) << 4))) = Pk.q;
      }
    }
    __syncthreads();

    // ---- C-GEMM: acc[i,f] = att[i,:] x H[:,f] ----
    f32x4 accC[3][4];
#pragma unroll
    for (int s = 0; s < 3; ++s)
#pragma unroll
      for (int n = 0; n < 4; ++n) accC[s][n] = (f32x4){0.f, 0.f, 0.f, 0.f};

    const unsigned short* ab = att + (size_t)gko * (ATT_R * ATT_S);
#pragma unroll 2
    for (int kst = 0; kst < 6; ++kst) {
      const int kk0 = kst * 32 + lg * 8;
      bf16x8 bfr[4];
#pragma unroll
      for (int n = 0; n < 4; ++n) {
        const int f = n * 16 + lr;
        bfr[n] = *(const bf16x8*)((const char*)Htl + ((f * 384 + kk0 * 2) ^ ((f & 7) << 4)));
      }
#pragma unroll
      for (int s = 0; s < 3; ++s) {
        const int mt = wv + 8 * s;
        if (mt < 21) {
          const bf16x8 af = *(const bf16x8*)(ab + (mt * 16 + lr) * ATT_S + kk0);
#pragma unroll
          for (int n = 0; n < 4; ++n)
            accC[s][n] = __builtin_amdgcn_mfma_f32_16x16x32_bf16(af, bfr[n], accC[s][n], 0, 0, 0);
        }
      }
    }
    // ---- epilogue: accO += leaky(hp) * cl[k] ----
#pragma unroll
    for (int s = 0; s < 3; ++s) {
      const int mt = wv + 8 * s;
      if (mt < 21) {
        const int i0 = mt * 16 + lg * 4;
#pragma unroll
        for (int r = 0; r < 4; ++r) {
          const float clv = cll[(i0 + r) * 4 + k];
#pragma unroll
          for (int n = 0; n < 4; ++n)
            accO[s][n][r] += leaky(accC[s][n][r]) * clv;
        }
      }
    }
  }

  // ---- final atomic accumulate ----
#pragma unroll
  for (int s = 0; s < 3; ++s) {
    const int mt = wv + 8 * s;
    if (mt < 21) {
      const int i0 = mt * 16 + lg * 4;
#pragma unroll
      for (int r = 0; r < 4; ++r) {
        const int i = i0 + r;
        if (i < V) {
          float* op = out + ((b * V + i) * T + t) * F + lr;
#pragma unroll
          for (int n = 0; n < 4; ++n)
            atomicAdd(op + n * 16, accO[s][n][r] * (1.0f / 3.0f));
        }
      }
    }
  }
}

}  // namespace

extern "C" void kernel_launch(void* const* d_in, const int* in_sizes, int n_in,
                              void* d_out, int out_size, void* d_ws, size_t ws_size,
                              hipStream_t stream) {
  const float* x   = (const float*)d_in[0];
  const int*   adj = (const int*)d_in[1];
  const float* W   = (const float*)d_in[2];
  const float* Wb  = (const float*)d_in[3];
  const float* Wt  = (const float*)d_in[4];
  const float* a   = (const float*)d_in[5];
  const float* cw  = (const float*)d_in[6];
  float* out = (float*)d_out;
  float* ws  = (float*)d_ws;

  float* ht = ws;                                         // HT_SZ floats
  unsigned short* attw = (unsigned short*)(ws + HT_SZ);   // 24*336*192 bf16 (~3.1 MB)

  hipMemsetAsync(out, 0, (size_t)OUT0 * sizeof(float), stream);
  k_cluster<<<B * V, 256, 0, stream>>>(x, cw, out);
  k_ht<<<G * K * 2 * V, 256, 0, stream>>>(x, W, Wb, Wt, ht);
  k_att<<<G * K * 2, 256, 0, stream>>>(ht, a, adj, attw);
  k_hp<<<B * T * G * 2, 512, 0, stream>>>(x, W, Wb, attw, out + OUT0, out);
}

// Round 3
// 397.317 us; speedup vs baseline: 7.1072x; 2.1329x over previous
//
#include <hip/hip_runtime.h>
#include <math.h>

namespace {

typedef __attribute__((ext_vector_type(8))) short bf16x8;
typedef __attribute__((ext_vector_type(4))) float f32x4;

constexpr int B = 16, V = 325, T = 12, F = 64, K = 4, G = 3;
constexpr int D = T * F;                   // 768
constexpr int ATT_R = 336;                 // padded rows (325 -> 336 = 21*16)
constexpr int ATT_S = 192;                 // padded K dim (163 -> 192 = 6*32), bf16
constexpr int OUT0 = B * V * T * F;        // 3,993,600 floats (gc_act)
constexpr int HT_SZ = G * K * 2 * V * F;   // 499,200 floats
constexpr float SLOPE_ = 325.0f;
constexpr float NEGINF = -9.0e15f;

__device__ __forceinline__ float leaky(float x) { return x >= 0.0f ? x : SLOPE_ * x; }

__device__ __forceinline__ unsigned short f2bf(float f) {
  unsigned int u = __float_as_uint(f);
  u = (u + 0x7fffu + ((u >> 16) & 1u)) >> 16;   // RNE
  return (unsigned short)u;
}
__device__ __forceinline__ float bf2f(unsigned short h) {
  return __uint_as_float((unsigned int)h << 16);
}

__device__ __forceinline__ float wsum(float v) {
#pragma unroll
  for (int m = 32; m >= 1; m >>= 1) v += __shfl_xor(v, m);
  return v;
}
__device__ __forceinline__ float wmax(float v) {
#pragma unroll
  for (int m = 32; m >= 1; m >>= 1) v = fmaxf(v, __shfl_xor(v, m));
  return v;
}

// ---------------------------------------------------------------------------
// K1: cluster[g,b,v,k] = softmax_k( dot(xv[b,v,:768], cw[g,k,:768]) )
// ---------------------------------------------------------------------------
__global__ __launch_bounds__(256) void k_cluster(const float* __restrict__ x,
                                                 const float* __restrict__ cw,
                                                 float* __restrict__ out) {
  const int bv = blockIdx.x;
  const int lane = threadIdx.x & 63, wave = threadIdx.x >> 6;
  __shared__ float lg[12];
  const float* xr = x + bv * D;
  for (int p = wave; p < 12; p += 4) {
    const float* wr = cw + p * D;
    float s = 0.f;
#pragma unroll
    for (int m = 0; m < 12; ++m) {
      const int d = lane + 64 * m;
      s = fmaf(xr[d], wr[d], s);
    }
    s = wsum(s);
    if (lane == 0) lg[p] = s;
  }
  __syncthreads();
  if (threadIdx.x < 3) {
    const int g = threadIdx.x;
    float m = lg[g * 4];
    for (int k = 1; k < 4; ++k) m = fmaxf(m, lg[g * 4 + k]);
    float e[4], s = 0.f;
    for (int k = 0; k < 4; ++k) { e[k] = expf(lg[g * 4 + k] - m); s += e[k]; }
    const float inv = 1.f / s;
    const int b = bv / V, v = bv % V;
    float* o = out + OUT0 + ((g * B + b) * V + v) * K;
    for (int k = 0; k < 4; ++k) o[k] = e[k] * inv;
  }
}

// ---------------------------------------------------------------------------
// K2 (MFMA, split-bf16 compensated): per block v, stage X[192][64] hi/lo once;
// loop 24 gko: stage W hi/lo, compute h = X.W^T via 3-term bf16 MFMA
// (rel err ~1e-5, fp32-equivalent), epilogue bias+leaky+Wt, reduce over
// (b,t) rows -> ht[gko,v,f].
// Fragment layouts as in k_hp (m89-verified). XOR swizzle (row&7)<<4.
// ---------------------------------------------------------------------------
__global__ __launch_bounds__(512, 4) void k_ht(const float* __restrict__ x,
                                               const float* __restrict__ W,
                                               const float* __restrict__ Wbias,
                                               const float* __restrict__ Wt,
                                               float* __restrict__ ht) {
  const int v = blockIdx.x;
  const int tid = threadIdx.x;
  const int lane = tid & 63;
  const int wv = tid >> 6;
  const int lr = lane & 15, lg = lane >> 4;
  const int n = wv & 3, half = wv >> 2;

  __shared__ unsigned short Xhi[192 * 64];   // 24 KB, swizzled
  __shared__ unsigned short Xlo[192 * 64];   // 24 KB
  __shared__ unsigned short Whi[64 * 64];    // 8 KB
  __shared__ unsigned short Wlo[64 * 64];    // 8 KB
  __shared__ float biasl[64];
  __shared__ float Wtl[12];
  __shared__ float red[4][2][16];

  // ---- stage X hi/lo (once; reused for all 24 gko) ----
  for (int idx = tid; idx < 192 * 8; idx += 512) {
    const int row = idx >> 3, c0 = (idx & 7) * 8;
    const int bb = row / 12, tt = row % 12;
    const float* xp = x + ((bb * V + v) * T + tt) * F + c0;
    const float4 x0 = *(const float4*)xp;
    const float4 x1 = *(const float4*)(xp + 4);
    const float vals[8] = {x0.x, x0.y, x0.z, x0.w, x1.x, x1.y, x1.z, x1.w};
    union { unsigned short u[8]; uint4 q; } H, L;
#pragma unroll
    for (int e = 0; e < 8; ++e) {
      const unsigned short hh = f2bf(vals[e]);
      H.u[e] = hh;
      L.u[e] = f2bf(vals[e] - bf2f(hh));
    }
    const int off = (row * 128 + c0 * 2) ^ ((row & 7) << 4);
    *(uint4*)((char*)Xhi + off) = H.q;
    *(uint4*)((char*)Xlo + off) = L.q;
  }

  for (int gko = 0; gko < 24; ++gko) {
    // ---- stage W hi/lo (exactly one 8-elem chunk per thread) ----
    {
      const int f = tid >> 3, c0 = (tid & 7) * 8;
      const float* wp = W + gko * (F * F) + f * 64 + c0;
      const float4 w0 = *(const float4*)wp;
      const float4 w1 = *(const float4*)(wp + 4);
      const float vals[8] = {w0.x, w0.y, w0.z, w0.w, w1.x, w1.y, w1.z, w1.w};
      union { unsigned short u[8]; uint4 q; } H, L;
#pragma unroll
      for (int e = 0; e < 8; ++e) {
        const unsigned short hh = f2bf(vals[e]);
        H.u[e] = hh;
        L.u[e] = f2bf(vals[e] - bf2f(hh));
      }
      const int off = (f * 128 + c0 * 2) ^ ((f & 7) << 4);
      *(uint4*)((char*)Whi + off) = H.q;
      *(uint4*)((char*)Wlo + off) = L.q;
      if (tid < 64) biasl[tid] = Wbias[gko * 64 + tid];
      else if (tid < 76) Wtl[tid - 64] = Wt[gko * 12 + (tid - 64)];
    }
    __syncthreads();

    // ---- compute: wave (n, half): n-tile n, M-tiles half*6..half*6+5 ----
    float psum = 0.f;
    const float bv = biasl[n * 16 + lr];
    const int offB0 = ((n * 16 + lr) * 128) ^ (((n * 16 + lr) & 7) << 4);
#pragma unroll
    for (int i = 0; i < 6; ++i) {
      const int mt = half * 6 + i;
      const int arow = mt * 16 + lr;
      const int offA0 = (arow * 128) ^ ((arow & 7) << 4);
      f32x4 acc = (f32x4){0.f, 0.f, 0.f, 0.f};
#pragma unroll
      for (int kst = 0; kst < 2; ++kst) {
        const int kb = (kst * 32 + lg * 8) * 2;  // byte offset within row
        const bf16x8 ah = *(const bf16x8*)((const char*)Xhi + (offA0 ^ kb));
        const bf16x8 al = *(const bf16x8*)((const char*)Xlo + (offA0 ^ kb));
        const bf16x8 bh = *(const bf16x8*)((const char*)Whi + (offB0 ^ kb));
        const bf16x8 bl = *(const bf16x8*)((const char*)Wlo + (offB0 ^ kb));
        acc = __builtin_amdgcn_mfma_f32_16x16x32_bf16(ah, bh, acc, 0, 0, 0);
        acc = __builtin_amdgcn_mfma_f32_16x16x32_bf16(ah, bl, acc, 0, 0, 0);
        acc = __builtin_amdgcn_mfma_f32_16x16x32_bf16(al, bh, acc, 0, 0, 0);
      }
#pragma unroll
      for (int r = 0; r < 4; ++r) {
        const int row = mt * 16 + lg * 4 + r;
        psum = fmaf(leaky(acc[r] + bv), Wtl[row % 12], psum);
      }
    }
    psum += __shfl_xor(psum, 16);
    psum += __shfl_xor(psum, 32);
    if (lg == 0) red[n][half][lr] = psum;
    __syncthreads();
    if (tid < 64)
      ht[(gko * V + v) * 64 + tid] =
          (red[tid >> 4][0][tid & 15] + red[tid >> 4][1][tid & 15]) * (1.0f / 16.0f);
    // next iteration's stage only rewrites W buffers (reads done before the
    // post-red barrier) and biasl (same-thread order for tid<64); red is
    // rewritten only after the next post-stage barrier.
    __syncthreads();
  }
}

// ---------------------------------------------------------------------------
// K3: att[gko, i, j] = softmax_j over masked leaky(s1[j]+s2[i]) -> bf16,
//     padded to [ATT_R=336][ATT_S=192] with zeros.
// ---------------------------------------------------------------------------
__global__ __launch_bounds__(256) void k_att(const float* __restrict__ ht,
                                             const float* __restrict__ a,
                                             const int* __restrict__ adj,
                                             unsigned short* __restrict__ att) {
  const int gko = blockIdx.x;
  const int o = gko & 1;
  const int g = gko >> 3;  // gko = ((g*4+k)*2+o)
  const int Vs = o ? 162 : 163;
  const int tid = threadIdx.x, lane = tid & 63, wave = tid >> 6;
  __shared__ float s1[163], s2[325];
  const float* htg = ht + gko * (V * F);
  const float* a1 = a + gko * 128;
  const float* a2 = a1 + 64;

  for (int d = wave; d < 325 + Vs; d += 4) {
    int row; const float* av;
    if (d < 325) { row = d;                 av = a2; }
    else         { row = o + 2 * (d - 325); av = a1; }
    float s = htg[row * 64 + lane] * av[lane];
    s = wsum(s);
    if (lane == 0) { if (d < 325) s2[d] = s; else s1[d - 325] = s; }
  }
  __syncthreads();

  const int* adjg = adj + g * (V * V);
  for (int i = wave; i < V; i += 4) {
    const float e0 = s2[i];
    float vj[3];
    float mx = NEGINF;
#pragma unroll
    for (int r = 0; r < 3; ++r) {
      const int j = lane + 64 * r;
      float val = NEGINF;
      if (j < Vs) {
        const float e = leaky(s1[j] + e0);
        const int ad = adjg[i * V + (o + 2 * j)];
        val = (ad > 0) ? e : NEGINF;
      }
      vj[r] = val;
      mx = fmaxf(mx, val);
    }
    mx = wmax(mx);
    float sum = 0.f, ex[3];
#pragma unroll
    for (int r = 0; r < 3; ++r) {
      const int j = lane + 64 * r;
      const float tt = (j < Vs) ? expf(vj[r] - mx) : 0.f;
      ex[r] = tt; sum += tt;
    }
    sum = wsum(sum);
    const float inv = 1.f / sum;
    unsigned short* ar = att + ((size_t)gko * ATT_R + i) * ATT_S;
#pragma unroll
    for (int r = 0; r < 3; ++r) {
      const int j = lane + 64 * r;  // covers 0..191 = ATT_S
      ar[j] = (j < Vs) ? f2bf(ex[r] * inv) : 0;
    }
  }
  // zero pad rows 325..335
  unsigned short* zb = att + ((size_t)gko * ATT_R + 325) * ATT_S;
  for (int idx = tid; idx < (ATT_R - V) * ATT_S; idx += 256) zb[idx] = 0;
}

// ---------------------------------------------------------------------------
// K4 (MFMA): per block (g,o,b,t), loop k:
//   H-build: H[j,f] = leaky(X[j,:].W[f,:] + b)  via mfma, bf16 -> LDS Ht[f][j]
//   C-GEMM : hp[i,f] = sum_j att_bf16[i,j] * H[j,f] via mfma
//   accO   += leaky(hp) * cluster[g,b,i,k]
// atomicAdd(out, accO/3).
// ---------------------------------------------------------------------------
__global__ __launch_bounds__(512, 2) void k_hp(const float* __restrict__ x,
                                               const float* __restrict__ W,
                                               const float* __restrict__ Wbias,
                                               const unsigned short* __restrict__ att,
                                               const float* __restrict__ cluster,
                                               float* __restrict__ out) {
  const int bid = blockIdx.x;
  const int o = bid & 1;
  const int g = (bid >> 1) % 3;
  const int bt = bid / 6;
  const int t = bt % 12;
  const int b = bt / 12;
  const int Vs = o ? 162 : 163;
  const int tid = threadIdx.x;
  const int lane = tid & 63;
  const int wv = tid >> 6;       // 8 waves
  const int lr = lane & 15;      // tile row/col
  const int lg = lane >> 4;      // k-group

  __shared__ unsigned short Xl[176 * 64];    // bf16, swizzled, 22.5 KB
  __shared__ unsigned short Wlb[64 * 64];    // bf16, swizzled, 8 KB
  __shared__ unsigned short Htl[64 * 192];   // bf16 H^T [f][j], swizzled, 24.6 KB
  __shared__ float biasl[64];
  __shared__ float cll[336 * 4];

  // ---- stage X as bf16 (rows >= Vs zero), swizzled ----
  for (int idx = tid; idx < 176 * 8; idx += 512) {
    const int j = idx >> 3, c0 = (idx & 7) * 8;
    union { unsigned short u[8]; uint4 q; } P;
    if (j < Vs) {
      const float* xp = x + ((b * V + (o + 2 * j)) * T + t) * F + c0;
      const float4 x0 = *(const float4*)xp;
      const float4 x1 = *(const float4*)(xp + 4);
      P.u[0] = f2bf(x0.x); P.u[1] = f2bf(x0.y); P.u[2] = f2bf(x0.z); P.u[3] = f2bf(x0.w);
      P.u[4] = f2bf(x1.x); P.u[5] = f2bf(x1.y); P.u[6] = f2bf(x1.z); P.u[7] = f2bf(x1.w);
    } else {
      P.q = make_uint4(0, 0, 0, 0);
    }
    *(uint4*)((char*)Xl + ((j * 128 + c0 * 2) ^ ((j & 7) << 4))) = P.q;
  }
  // ---- stage cluster weights (i >= 325 zero) ----
  for (int i = tid; i < 336; i += 512) {
    float4 c4 = make_float4(0.f, 0.f, 0.f, 0.f);
    if (i < V) c4 = *(const float4*)(cluster + ((g * B + b) * V + i) * K);
    *(float4*)&cll[i * 4] = c4;
  }
  // ---- zero Ht (covers K-pad cols 176..191 permanently) ----
  for (int idx = tid; idx < (64 * 192) / 8; idx += 512)
    ((uint4*)Htl)[idx] = make_uint4(0, 0, 0, 0);

  f32x4 accO[3][4];
#pragma unroll
  for (int s = 0; s < 3; ++s)
#pragma unroll
    for (int n = 0; n < 4; ++n) accO[s][n] = (f32x4){0.f, 0.f, 0.f, 0.f};

  for (int k = 0; k < K; ++k) {
    const int gko = (g * K + k) * 2 + o;
    __syncthreads();  // prev C-GEMM readers of Htl/Wlb done
    // ---- stage W (bf16, swizzled) + bias ----
    {
      const int f = tid >> 3, c0 = (tid & 7) * 8;
      const float* wp = W + gko * (F * F) + f * 64 + c0;
      const float4 w0 = *(const float4*)wp;
      const float4 w1 = *(const float4*)(wp + 4);
      union { unsigned short u[8]; uint4 q; } P;
      P.u[0] = f2bf(w0.x); P.u[1] = f2bf(w0.y); P.u[2] = f2bf(w0.z); P.u[3] = f2bf(w0.w);
      P.u[4] = f2bf(w1.x); P.u[5] = f2bf(w1.y); P.u[6] = f2bf(w1.z); P.u[7] = f2bf(w1.w);
      *(uint4*)((char*)Wlb + ((f * 128 + c0 * 2) ^ ((f & 7) << 4))) = P.q;
      if (tid < 64) biasl[tid] = Wbias[gko * 64 + tid];
    }
    __syncthreads();

    // ---- H-build: 11 Mtiles x 4 Ntiles, K=64 (2 steps) ----
    for (int s = 0; s < 6; ++s) {
      const int p = wv + 8 * s;
      if (p < 44) {
        const int mt = p >> 2, n = p & 3;
        f32x4 acc = (f32x4){0.f, 0.f, 0.f, 0.f};
#pragma unroll
        for (int kst = 0; kst < 2; ++kst) {
          const int j = mt * 16 + lr, k0 = kst * 32 + lg * 8;
          const bf16x8 af = *(const bf16x8*)((const char*)Xl + ((j * 128 + k0 * 2) ^ ((j & 7) << 4)));
          const int f = n * 16 + lr;
          const bf16x8 bf = *(const bf16x8*)((const char*)Wlb + ((f * 128 + k0 * 2) ^ ((f & 7) << 4)));
          acc = __builtin_amdgcn_mfma_f32_16x16x32_bf16(af, bf, acc, 0, 0, 0);
        }
        const int f = n * 16 + lr;
        const float bv = biasl[f];
        const int j0 = mt * 16 + lg * 4;
        union { unsigned short u[4]; uint2 q; } Pk;
#pragma unroll
        for (int r = 0; r < 4; ++r) {
          const float val = leaky(acc[r] + bv);
          Pk.u[r] = (j0 + r < Vs) ? f2bf(val) : 0;
        }
        *(uint2*)((char*)Htl + ((f * 384 + j0 * 2) ^ ((f & 7) << 4))) = Pk.q;
      }
    }
    __syncthreads();

    // ---- C-GEMM: acc[i,f] = att[i,:] x H[:,f] ----
    f32x4 accC[3][4];
#pragma unroll
    for (int s = 0; s < 3; ++s)
#pragma unroll
      for (int n = 0; n < 4; ++n) accC[s][n] = (f32x4){0.f, 0.f, 0.f, 0.f};

    const unsigned short* ab = att + (size_t)gko * (ATT_R * ATT_S);
#pragma unroll 2
    for (int kst = 0; kst < 6; ++kst) {
      const int kk0 = kst * 32 + lg * 8;
      bf16x8 bfr[4];
#pragma unroll
      for (int n = 0; n < 4; ++n) {
        const int f = n * 16 + lr;
        bfr[n] = *(const bf16x8*)((const char*)Htl + ((f * 384 + kk0 * 2) ^ ((f & 7) << 4)));
      }
#pragma unroll
      for (int s = 0; s < 3; ++s) {
        const int mt = wv + 8 * s;
        if (mt < 21) {
          const bf16x8 af = *(const bf16x8*)(ab + (mt * 16 + lr) * ATT_S + kk0);
#pragma unroll
          for (int n = 0; n < 4; ++n)
            accC[s][n] = __builtin_amdgcn_mfma_f32_16x16x32_bf16(af, bfr[n], accC[s][n], 0, 0, 0);
        }
      }
    }
    // ---- epilogue: accO += leaky(hp) * cl[k] ----
#pragma unroll
    for (int s = 0; s < 3; ++s) {
      const int mt = wv + 8 * s;
      if (mt < 21) {
        const int i0 = mt * 16 + lg * 4;
#pragma unroll
        for (int r = 0; r < 4; ++r) {
          const float clv = cll[(i0 + r) * 4 + k];
#pragma unroll
          for (int n = 0; n < 4; ++n)
            accO[s][n][r] += leaky(accC[s][n][r]) * clv;
        }
      }
    }
  }

  // ---- final atomic accumulate ----
#pragma unroll
  for (int s = 0; s < 3; ++s) {
    const int mt = wv + 8 * s;
    if (mt < 21) {
      const int i0 = mt * 16 + lg * 4;
#pragma unroll
      for (int r = 0; r < 4; ++r) {
        const int i = i0 + r;
        if (i < V) {
          float* op = out + ((b * V + i) * T + t) * F + lr;
#pragma unroll
          for (int n = 0; n < 4; ++n)
            atomicAdd(op + n * 16, accO[s][n][r] * (1.0f / 3.0f));
        }
      }
    }
  }
}

}  // namespace

extern "C" void kernel_launch(void* const* d_in, const int* in_sizes, int n_in,
                              void* d_out, int out_size, void* d_ws, size_t ws_size,
                              hipStream_t stream) {
  const float* x   = (const float*)d_in[0];
  const int*   adj = (const int*)d_in[1];
  const float* W   = (const float*)d_in[2];
  const float* Wb  = (const float*)d_in[3];
  const float* Wt  = (const float*)d_in[4];
  const float* a   = (const float*)d_in[5];
  const float* cw  = (const float*)d_in[6];
  float* out = (float*)d_out;
  float* ws  = (float*)d_ws;

  float* ht = ws;                                         // HT_SZ floats
  unsigned short* attw = (unsigned short*)(ws + HT_SZ);   // 24*336*192 bf16 (~3.1 MB)

  hipMemsetAsync(out, 0, (size_t)OUT0 * sizeof(float), stream);
  k_cluster<<<B * V, 256, 0, stream>>>(x, cw, out);
  k_ht<<<V, 512, 0, stream>>>(x, W, Wb, Wt, ht);
  k_att<<<G * K * 2, 256, 0, stream>>>(ht, a, adj, attw);
  k_hp<<<B * T * G * 2, 512, 0, stream>>>(x, W, Wb, attw, out + OUT0, out);
}